// Round 1
// baseline (51.375 us; speedup 1.0000x reference)
//
#include <hip/hip_runtime.h>
#include <stdint.h>

// ---------------- problem constants ----------------
#define B_ROWS 16384
#define LATD   128
#define HIDD   1024
#define NPAD   320     // padded output cols (294 real)
#define NREAL  294

typedef __bf16 bf16x8 __attribute__((ext_vector_type(8)));
typedef float  f32x4  __attribute__((ext_vector_type(4)));
typedef unsigned short ushort8v __attribute__((ext_vector_type(8)));

// ---------------- threefry2x32 (matches JAX, partitionable default) ----------------
struct TF2 { unsigned int a, b; };

#define TF_R(x0,x1,r) { x0 += x1; x1 = ((x1 << (r)) | (x1 >> (32 - (r)))); x1 ^= x0; }

__host__ __device__ constexpr TF2 threefry2x32(unsigned k0, unsigned k1, unsigned c0, unsigned c1) {
  unsigned ks2 = k0 ^ k1 ^ 0x1BD11BDAu;
  unsigned x0 = c0 + k0, x1 = c1 + k1;
  TF_R(x0,x1,13) TF_R(x0,x1,15) TF_R(x0,x1,26) TF_R(x0,x1,6)
  x0 += k1;  x1 += ks2 + 1u;
  TF_R(x0,x1,17) TF_R(x0,x1,29) TF_R(x0,x1,16) TF_R(x0,x1,24)
  x0 += ks2; x1 += k0 + 2u;
  TF_R(x0,x1,13) TF_R(x0,x1,15) TF_R(x0,x1,26) TF_R(x0,x1,6)
  x0 += k0;  x1 += k1 + 3u;
  TF_R(x0,x1,17) TF_R(x0,x1,29) TF_R(x0,x1,16) TF_R(x0,x1,24)
  x0 += k1;  x1 += ks2 + 4u;
  TF_R(x0,x1,13) TF_R(x0,x1,15) TF_R(x0,x1,26) TF_R(x0,x1,6)
  x0 += ks2; x1 += k0 + 5u;
  return {x0, x1};
}

// nk = split(key(1), 3) with foldlike split: nk[i] = threefry((0,1), 0, i)
constexpr TF2 NK0 = threefry2x32(0u, 1u, 0u, 0u);  // bin heads
constexpr TF2 NK1 = threefry2x32(0u, 1u, 0u, 1u);  // like heads
constexpr TF2 NK2 = threefry2x32(0u, 1u, 0u, 2u);  // mask heads

__device__ __forceinline__ unsigned short f2bf(float f) {
  unsigned u = __float_as_uint(f);
  return (unsigned short)((u + 0x7fffu + ((u >> 16) & 1u)) >> 16);
}

// ---------------- prep: build bf16 transposed weights + fused bias in d_ws ----------------
// W1t  [1024][128]  bf16  (n-major, k contiguous)
// Wallt[320][1024]  bf16  (n-major, k contiguous; cols >=294 zero)
// ball [320]        f32
__global__ void prep_kernel(const float* __restrict__ W1,
                            const float* __restrict__ Wnum, const float* __restrict__ Wcat,
                            const float* __restrict__ Wbin, const float* __restrict__ Wlike,
                            const float* __restrict__ Wmask,
                            const float* __restrict__ bnum, const float* __restrict__ bcat,
                            const float* __restrict__ bbin, const float* __restrict__ blike,
                            const float* __restrict__ bmask,
                            unsigned short* __restrict__ W1t,
                            unsigned short* __restrict__ Wallt,
                            float* __restrict__ ball) {
  int idx = blockIdx.x * 256 + threadIdx.x;
  if (idx < 131072) {                      // W1t
    int n = idx >> 7, k = idx & 127;
    W1t[idx] = f2bf(W1[k * HIDD + n]);
  } else if (idx < 131072 + 327680) {      // Wallt
    int i = idx - 131072;
    int n = i >> 10, k = i & 1023;
    float v = 0.f;
    if (n < 32)       v = Wnum [k * 32  + n];
    else if (n < 230) v = Wcat [k * 198 + (n - 32)];
    else if (n < 238) v = Wbin [k * 8   + (n - 230)];
    else if (n < 240) v = Wlike[k * 2   + (n - 238)];
    else if (n < 294) v = Wmask[k * 54  + (n - 240)];
    Wallt[i] = f2bf(v);
  } else if (idx < 131072 + 327680 + 320) { // ball
    int n = idx - (131072 + 327680);
    float v = 0.f;
    if (n < 32)       v = bnum [n];
    else if (n < 230) v = bcat [n - 32];
    else if (n < 238) v = bbin [n - 230];
    else if (n < 240) v = blike[n - 238];
    else if (n < 294) v = bmask[n - 240];
    ball[n] = v;
  }
}

// ---------------- main fused decoder ----------------
// 256 WGs x 256 threads (4 waves). Each WG owns 64 rows.
// LDS: zs [64][136] bf16 (17408 B) | hs0/hs1 [64][136] bf16 (2x17408 B)
// reused after GEMM as outs [64][321] f32 (82176 B)
__global__ __launch_bounds__(256, 1) void decoder_kernel(
    const float* __restrict__ z, const float* __restrict__ b1,
    const unsigned short* __restrict__ W1t, const unsigned short* __restrict__ Wallt,
    const float* __restrict__ ball, float* __restrict__ out) {
  __shared__ __align__(16) unsigned char smem[82176];
  unsigned short* zs  = (unsigned short*)smem;             // [64][136]
  unsigned short* hs0 = (unsigned short*)(smem + 17408);
  unsigned short* hs1 = (unsigned short*)(smem + 34816);
  float* outs = (float*)smem;                              // [64][321]

  const int tid  = threadIdx.x;
  const int lane = tid & 63;
  const int wv   = tid >> 6;        // wave 0..3, owns out cols [wv*80, wv*80+80)
  const int l15  = lane & 15;
  const int l4   = lane >> 4;
  const int r0   = blockIdx.x * 64;

  // ---- stage z tile -> LDS bf16 ----
  #pragma unroll
  for (int it = 0; it < 4; ++it) {
    int ch  = tid + it * 256;       // 0..1023
    int row = ch >> 4;
    int k0  = (ch & 15) * 8;
    const float* src = z + (size_t)(r0 + row) * LATD + k0;
    float4 f0 = *(const float4*)src;
    float4 f1 = *(const float4*)(src + 4);
    ushort8v p;
    p[0] = f2bf(f0.x); p[1] = f2bf(f0.y); p[2] = f2bf(f0.z); p[3] = f2bf(f0.w);
    p[4] = f2bf(f1.x); p[5] = f2bf(f1.y); p[6] = f2bf(f1.z); p[7] = f2bf(f1.w);
    *(ushort8v*)(zs + row * 136 + k0) = p;
  }
  __syncthreads();

  // ---- z A-fragments (kept in regs; reused by all 8 chunks) ----
  bf16x8 za[4][4];
  #pragma unroll
  for (int rt = 0; rt < 4; ++rt)
    #pragma unroll
    for (int ks = 0; ks < 4; ++ks)
      za[rt][ks] = *(const bf16x8*)(zs + (rt * 16 + l15) * 136 + ks * 32 + l4 * 8);

  float bias2[5];
  #pragma unroll
  for (int ct = 0; ct < 5; ++ct) bias2[ct] = ball[wv * 80 + ct * 16 + l15];

  f32x4 acc2[4][5] = {};

  #pragma unroll
  for (int c = 0; c < 8; ++c) {
    const int hbase = c * 128 + wv * 32;
    // ---- first GEMM: h_chunk[64][128], this wave computes cols [wv*32, wv*32+32) ----
    bf16x8 wb1[2][4];
    #pragma unroll
    for (int ct = 0; ct < 2; ++ct)
      #pragma unroll
      for (int ks = 0; ks < 4; ++ks)
        wb1[ct][ks] = *(const bf16x8*)(W1t + (size_t)(hbase + ct * 16 + l15) * 128 + ks * 32 + l4 * 8);
    f32x4 acc1[4][2] = {};
    #pragma unroll
    for (int ks = 0; ks < 4; ++ks)
      #pragma unroll
      for (int rt = 0; rt < 4; ++rt)
        #pragma unroll
        for (int ct = 0; ct < 2; ++ct)
          acc1[rt][ct] = __builtin_amdgcn_mfma_f32_16x16x32_bf16(za[rt][ks], wb1[ct][ks], acc1[rt][ct], 0, 0, 0);
    float bb0  = b1[hbase + l15];
    float bb1v = b1[hbase + 16 + l15];
    unsigned short* hw = (c & 1) ? hs1 : hs0;
    #pragma unroll
    for (int rt = 0; rt < 4; ++rt)
      #pragma unroll
      for (int ct = 0; ct < 2; ++ct) {
        float bb = ct ? bb1v : bb0;
        #pragma unroll
        for (int j = 0; j < 4; ++j) {
          float v = fmaxf(acc1[rt][ct][j] + bb, 0.f);
          hw[(rt * 16 + l4 * 4 + j) * 136 + wv * 32 + ct * 16 + l15] = f2bf(v);
        }
      }
    __syncthreads();
    // ---- second GEMM: acc2 += h_chunk @ Wall[chunk, :] ----
    #pragma unroll
    for (int ks = 0; ks < 4; ++ks) {
      bf16x8 ha[4];
      #pragma unroll
      for (int rt = 0; rt < 4; ++rt)
        ha[rt] = *(const bf16x8*)(hw + (rt * 16 + l15) * 136 + ks * 32 + l4 * 8);
      bf16x8 wb2[5];
      #pragma unroll
      for (int ct = 0; ct < 5; ++ct)
        wb2[ct] = *(const bf16x8*)(Wallt + (size_t)(wv * 80 + ct * 16 + l15) * 1024 + c * 128 + ks * 32 + l4 * 8);
      #pragma unroll
      for (int rt = 0; rt < 4; ++rt)
        #pragma unroll
        for (int ct = 0; ct < 5; ++ct)
          acc2[rt][ct] = __builtin_amdgcn_mfma_f32_16x16x32_bf16(ha[rt], wb2[ct], acc2[rt][ct], 0, 0, 0);
    }
  }
  __syncthreads();   // done with zs/hs; reuse LDS as outs

  // ---- dump accumulators (+bias) to LDS [64][321] ----
  #pragma unroll
  for (int rt = 0; rt < 4; ++rt)
    #pragma unroll
    for (int ct = 0; ct < 5; ++ct)
      #pragma unroll
      for (int j = 0; j < 4; ++j)
        outs[(rt * 16 + l4 * 4 + j) * 321 + wv * 80 + ct * 16 + l15] = acc2[rt][ct][j] + bias2[ct];
  __syncthreads();

  // ---- write num + cat blocks (row-major [B, card] chunks, flat contiguous copy) ----
  {
    constexpr int cards[13] = {32,10,20,15,8,30,12,5,25,6,40,18,9};
    constexpr int cbase[13] = {0,32,42,62,77,85,115,127,132,157,163,203,221};
    #pragma unroll
    for (int blk = 0; blk < 13; ++blk) {
      const int card = cards[blk];
      const int cb   = cbase[blk];
      float* gout = out + (size_t)B_ROWS * cb + (size_t)r0 * card;
      for (int v = tid; v < card * 16; v += 256) {
        int g = v * 4;
        float vbuf[4];
        #pragma unroll
        for (int e = 0; e < 4; ++e) {
          int ge = g + e;
          int brow = ge / card;          // card is compile-time after unroll
          int j = ge - brow * card;
          vbuf[e] = outs[brow * 321 + cb + j];
        }
        *(float4*)(gout + g) = *(float4*)vbuf;
      }
    }
  }

  // ---- gumbel-sigmoid heads: cols 230..293, out[B*c + b] (col-major blocks) ----
  {
    int c   = 230 + (tid >> 2);
    int rqb = (tid & 3) * 16;
    unsigned ka, kb; int Nh, head;
    if (c < 238)      { ka = NK0.a; kb = NK0.b; Nh = 8;  head = c - 230; }
    else if (c < 240) { ka = NK1.a; kb = NK1.b; Nh = 2;  head = c - 238; }
    else              { ka = NK2.a; kb = NK2.b; Nh = 54; head = c - 240; }
    float* gout = out + (size_t)B_ROWS * c + r0 + rqb;
    #pragma unroll
    for (int q = 0; q < 4; ++q) {
      float vbuf[4];
      #pragma unroll
      for (int e = 0; e < 4; ++e) {
        int rl = rqb + q * 4 + e;
        float x = outs[rl * 321 + c];
        unsigned j = (unsigned)((r0 + rl) * Nh + head);
        TF2 t = threefry2x32(ka, kb, 0u, j);
        unsigned bits = t.a ^ t.b;                      // partitionable: bits1 ^ bits2
        float u  = __uint_as_float((bits >> 9) | 0x3f800000u) - 1.0f;
        float gn = -logf(-logf(u + 1e-20f) + 1e-20f);
        vbuf[e] = 1.0f / (1.0f + expf(-(x + gn)));
      }
      *(float4*)(gout + q * 4) = *(float4*)vbuf;
    }
  }
}

// ---------------- launch ----------------
extern "C" void kernel_launch(void* const* d_in, const int* in_sizes, int n_in,
                              void* d_out, int out_size, void* d_ws, size_t ws_size,
                              hipStream_t stream) {
  const float* z     = (const float*)d_in[0];
  const float* W1    = (const float*)d_in[1];
  const float* b1    = (const float*)d_in[2];
  const float* Wnum  = (const float*)d_in[3];
  const float* bnum  = (const float*)d_in[4];
  const float* Wcat  = (const float*)d_in[5];
  const float* bcat  = (const float*)d_in[6];
  const float* Wbin  = (const float*)d_in[7];
  const float* bbin  = (const float*)d_in[8];
  const float* Wlike = (const float*)d_in[9];
  const float* blike = (const float*)d_in[10];
  const float* Wmask = (const float*)d_in[11];
  const float* bmask = (const float*)d_in[12];

  unsigned short* W1t   = (unsigned short*)d_ws;            // 131072 bf16
  unsigned short* Wallt = W1t + 131072;                     // 327680 bf16
  float*          ball  = (float*)(Wallt + 327680);         // 320 f32

  const int total = 131072 + 327680 + 320;
  prep_kernel<<<(total + 255) / 256, 256, 0, stream>>>(
      W1, Wnum, Wcat, Wbin, Wlike, Wmask, bnum, bcat, bbin, blike, bmask,
      W1t, Wallt, ball);

  decoder_kernel<<<B_ROWS / 64, 256, 0, stream>>>(
      z, b1, W1t, Wallt, ball, (float*)d_out);
}

// Round 2
// 34.116 us; speedup vs baseline: 1.5059x; 1.5059x over previous
//
#include <hip/hip_runtime.h>
#include <stdint.h>

// ---------------- problem constants ----------------
#define B_ROWS 16384
#define LATD   128
#define HIDD   1024

typedef __bf16 bf16x8 __attribute__((ext_vector_type(8)));
typedef float  f32x4  __attribute__((ext_vector_type(4)));
typedef unsigned short ushort8v __attribute__((ext_vector_type(8)));

// ---------------- threefry2x32 (matches JAX, partitionable default) ----------------
struct TF2 { unsigned int a, b; };

#define TF_R(x0,x1,r) { x0 += x1; x1 = ((x1 << (r)) | (x1 >> (32 - (r)))); x1 ^= x0; }

__host__ __device__ constexpr TF2 threefry2x32(unsigned k0, unsigned k1, unsigned c0, unsigned c1) {
  unsigned ks2 = k0 ^ k1 ^ 0x1BD11BDAu;
  unsigned x0 = c0 + k0, x1 = c1 + k1;
  TF_R(x0,x1,13) TF_R(x0,x1,15) TF_R(x0,x1,26) TF_R(x0,x1,6)
  x0 += k1;  x1 += ks2 + 1u;
  TF_R(x0,x1,17) TF_R(x0,x1,29) TF_R(x0,x1,16) TF_R(x0,x1,24)
  x0 += ks2; x1 += k0 + 2u;
  TF_R(x0,x1,13) TF_R(x0,x1,15) TF_R(x0,x1,26) TF_R(x0,x1,6)
  x0 += k0;  x1 += k1 + 3u;
  TF_R(x0,x1,17) TF_R(x0,x1,29) TF_R(x0,x1,16) TF_R(x0,x1,24)
  x0 += k1;  x1 += ks2 + 4u;
  TF_R(x0,x1,13) TF_R(x0,x1,15) TF_R(x0,x1,26) TF_R(x0,x1,6)
  x0 += ks2; x1 += k0 + 5u;
  return {x0, x1};
}

constexpr TF2 NK0 = threefry2x32(0u, 1u, 0u, 0u);  // bin heads
constexpr TF2 NK1 = threefry2x32(0u, 1u, 0u, 1u);  // like heads
constexpr TF2 NK2 = threefry2x32(0u, 1u, 0u, 2u);  // mask heads

__device__ __forceinline__ unsigned short f2bf(float f) {
  unsigned u = __float_as_uint(f);
  return (unsigned short)((u + 0x7fffu + ((u >> 16) & 1u)) >> 16);
}

// ---------------- prep: fragment-linear packed bf16 weights in d_ws ----------------
// W1p : 256 frags (nt 0..63 x ks 0..3), each frag = 64 lanes x 8 bf16 (contiguous 1 KB)
//        element (f, l, j): n = (f>>2)*16 + (l&15); k = (f&3)*32 + (l>>4)*8 + j; src W1[k][n]
// Wallp: 640 frags (nt 0..19 x kt 0..31), same intra-frag layout over fused-W columns
// ball : 320 f32 fused bias
__global__ void prep_kernel(const float* __restrict__ W1,
                            const float* __restrict__ Wnum, const float* __restrict__ Wcat,
                            const float* __restrict__ Wbin, const float* __restrict__ Wlike,
                            const float* __restrict__ Wmask,
                            const float* __restrict__ bnum, const float* __restrict__ bcat,
                            const float* __restrict__ bbin, const float* __restrict__ blike,
                            const float* __restrict__ bmask,
                            unsigned short* __restrict__ W1p,
                            unsigned short* __restrict__ Wallp,
                            float* __restrict__ ball) {
  int t = blockIdx.x * 256 + threadIdx.x;
  if (t < 16384) {                         // W1p: 16384 threads x 8 elems
    int f = t >> 6, l = t & 63;
    int n = (f >> 2) * 16 + (l & 15);
    int kk0 = (f & 3) * 32 + (l >> 4) * 8;
    ushort8v p;
    #pragma unroll
    for (int j = 0; j < 8; ++j) p[j] = f2bf(W1[(size_t)(kk0 + j) * HIDD + n]);
    *(ushort8v*)(W1p + (size_t)t * 8) = p;
  } else if (t < 16384 + 40960) {          // Wallp: 40960 threads x 8 elems
    int t2 = t - 16384;
    int g = t2 >> 6, l = t2 & 63;
    int nt = g >> 5, kt = g & 31;
    int n = nt * 16 + (l & 15);
    int kk0 = kt * 32 + (l >> 4) * 8;
    ushort8v p;
    #pragma unroll
    for (int j = 0; j < 8; ++j) {
      int kk = kk0 + j;
      float v = 0.f;
      if (n < 32)       v = Wnum [(size_t)kk * 32  + n];
      else if (n < 230) v = Wcat [(size_t)kk * 198 + (n - 32)];
      else if (n < 238) v = Wbin [(size_t)kk * 8   + (n - 230)];
      else if (n < 240) v = Wlike[(size_t)kk * 2   + (n - 238)];
      else if (n < 294) v = Wmask[(size_t)kk * 54  + (n - 240)];
      p[j] = f2bf(v);
    }
    *(ushort8v*)(Wallp + (size_t)t2 * 8) = p;
  } else if (t < 16384 + 40960 + 320) {    // ball
    int n = t - (16384 + 40960);
    float v = 0.f;
    if (n < 32)       v = bnum [n];
    else if (n < 230) v = bcat [n - 32];
    else if (n < 238) v = bbin [n - 230];
    else if (n < 240) v = blike[n - 238];
    else if (n < 294) v = bmask[n - 240];
    ball[n] = v;
  }
}

// ---------------- main fused decoder ----------------
// 256 WGs x 512 threads (8 waves). WG owns 64 rows.
// wave = (wk, wc): wk = chunk-half {0,1} (chunks 4wk..4wk+3), wc = col quarter (80 cols).
// LDS: zs[64][136] bf16 | hs0,hs1[64][136] bf16 (one per wk group); reused as outs[64][321] f32
__global__ __launch_bounds__(512, 2) void decoder_kernel(
    const float* __restrict__ z, const float* __restrict__ b1,
    const unsigned short* __restrict__ W1p, const unsigned short* __restrict__ Wallp,
    const float* __restrict__ ball, float* __restrict__ out) {
  __shared__ __align__(16) unsigned char smem[82176];
  unsigned short* zs  = (unsigned short*)smem;             // [64][136]
  unsigned short* hs0 = (unsigned short*)(smem + 17408);
  unsigned short* hs1 = (unsigned short*)(smem + 34816);
  float* outs = (float*)smem;                              // [64][321]

  const int tid  = threadIdx.x;
  const int lane = tid & 63;
  const int wv   = tid >> 6;        // 0..7
  const int wc   = wv & 3;          // col quarter
  const int wk   = wv >> 2;         // chunk half
  const int l15  = lane & 15;
  const int l4   = lane >> 4;
  const int r0   = blockIdx.x * 64;

  // ---- stage z tile -> LDS bf16 ----
  #pragma unroll
  for (int it = 0; it < 2; ++it) {
    int ch  = tid + it * 512;       // 0..1023
    int row = ch >> 4;
    int k0  = (ch & 15) * 8;
    const float* src = z + (size_t)(r0 + row) * LATD + k0;
    float4 f0 = *(const float4*)src;
    float4 f1 = *(const float4*)(src + 4);
    ushort8v p;
    p[0] = f2bf(f0.x); p[1] = f2bf(f0.y); p[2] = f2bf(f0.z); p[3] = f2bf(f0.w);
    p[4] = f2bf(f1.x); p[5] = f2bf(f1.y); p[6] = f2bf(f1.z); p[7] = f2bf(f1.w);
    *(ushort8v*)(zs + row * 136 + k0) = p;
  }

  // ---- preload biases (L2-resident scalars, off critical path) ----
  float bb[4][2];
  #pragma unroll
  for (int i = 0; i < 4; ++i)
    #pragma unroll
    for (int ct = 0; ct < 2; ++ct)
      bb[i][ct] = b1[(wk * 4 + i) * 128 + wc * 32 + ct * 16 + l15];
  float bias2[5];
  #pragma unroll
  for (int ct = 0; ct < 5; ++ct) bias2[ct] = ball[wc * 80 + ct * 16 + l15];

  unsigned short* hw = wk ? hs1 : hs0;
  f32x4 acc2[4][5] = {};

  __syncthreads();

  #pragma unroll
  for (int i = 0; i < 4; ++i) {
    const int c = wk * 4 + i;
    // ---- first GEMM: h[64][32 cols @ wc] for my chunk ----
    bf16x8 wb1[2][4];
    #pragma unroll
    for (int ct = 0; ct < 2; ++ct)
      #pragma unroll
      for (int ks = 0; ks < 4; ++ks)
        wb1[ct][ks] = *(const bf16x8*)(W1p + (size_t)(((c * 8 + wc * 2 + ct) * 4 + ks) * 64 + lane) * 8);
    f32x4 acc1[4][2] = {};
    #pragma unroll
    for (int ks = 0; ks < 4; ++ks) {
      bf16x8 za[4];
      #pragma unroll
      for (int rt = 0; rt < 4; ++rt)
        za[rt] = *(const bf16x8*)(zs + (rt * 16 + l15) * 136 + ks * 32 + l4 * 8);
      #pragma unroll
      for (int rt = 0; rt < 4; ++rt)
        #pragma unroll
        for (int ct = 0; ct < 2; ++ct)
          acc1[rt][ct] = __builtin_amdgcn_mfma_f32_16x16x32_bf16(za[rt], wb1[ct][ks], acc1[rt][ct], 0, 0, 0);
    }
    // ---- issue second-GEMM weight loads now (land during pack + barrier) ----
    bf16x8 wb2[5][4];
    #pragma unroll
    for (int ct = 0; ct < 5; ++ct)
      #pragma unroll
      for (int ks = 0; ks < 4; ++ks)
        wb2[ct][ks] = *(const bf16x8*)(Wallp + (size_t)(((wc * 5 + ct) * 32 + c * 4 + ks) * 64 + lane) * 8);
    __syncthreads();   // prior iteration's hs reads complete
    #pragma unroll
    for (int rt = 0; rt < 4; ++rt)
      #pragma unroll
      for (int ct = 0; ct < 2; ++ct)
        #pragma unroll
        for (int j = 0; j < 4; ++j) {
          float v = fmaxf(acc1[rt][ct][j] + bb[i][ct], 0.f);
          hw[(rt * 16 + l4 * 4 + j) * 136 + wc * 32 + ct * 16 + l15] = f2bf(v);
        }
    __syncthreads();   // h visible to my wk group
    // ---- second GEMM: acc2 += h_chunk @ Wall[chunk, wc-cols] ----
    #pragma unroll
    for (int ks = 0; ks < 4; ++ks) {
      bf16x8 ha[4];
      #pragma unroll
      for (int rt = 0; rt < 4; ++rt)
        ha[rt] = *(const bf16x8*)(hw + (rt * 16 + l15) * 136 + ks * 32 + l4 * 8);
      #pragma unroll
      for (int rt = 0; rt < 4; ++rt)
        #pragma unroll
        for (int ct = 0; ct < 5; ++ct)
          acc2[rt][ct] = __builtin_amdgcn_mfma_f32_16x16x32_bf16(ha[rt], wb2[ct][ks], acc2[rt][ct], 0, 0, 0);
    }
  }
  __syncthreads();   // all hs/zs reads done; LDS becomes outs

  // ---- 2-way wk reduction into outs[64][321] ----
  if (wk == 0) {
    #pragma unroll
    for (int rt = 0; rt < 4; ++rt)
      #pragma unroll
      for (int ct = 0; ct < 5; ++ct)
        #pragma unroll
        for (int j = 0; j < 4; ++j)
          outs[(rt * 16 + l4 * 4 + j) * 321 + wc * 80 + ct * 16 + l15] = acc2[rt][ct][j] + bias2[ct];
  }
  __syncthreads();
  if (wk == 1) {
    #pragma unroll
    for (int rt = 0; rt < 4; ++rt)
      #pragma unroll
      for (int ct = 0; ct < 5; ++ct)
        #pragma unroll
        for (int j = 0; j < 4; ++j)
          outs[(rt * 16 + l4 * 4 + j) * 321 + wc * 80 + ct * 16 + l15] += acc2[rt][ct][j];
  }
  __syncthreads();

  // ---- write num + cat blocks (row-major [B, card] chunks, contiguous float4) ----
  {
    constexpr int cards[13] = {32,10,20,15,8,30,12,5,25,6,40,18,9};
    constexpr int cbase[13] = {0,32,42,62,77,85,115,127,132,157,163,203,221};
    #pragma unroll
    for (int blk = 0; blk < 13; ++blk) {
      const int card = cards[blk];
      const int cb   = cbase[blk];
      float* gout = out + (size_t)B_ROWS * cb + (size_t)r0 * card;
      for (int v = tid; v < card * 16; v += 512) {
        int g = v * 4;
        float vbuf[4];
        #pragma unroll
        for (int e = 0; e < 4; ++e) {
          int ge = g + e;
          int brow = ge / card;          // compile-time card -> magic mul
          int j = ge - brow * card;
          vbuf[e] = outs[brow * 321 + cb + j];
        }
        *(float4*)(gout + g) = *(float4*)vbuf;
      }
    }
  }

  // ---- gumbel-sigmoid heads: cols 230..293, out[B*c + b] ----
  {
    int c = 230 + (tid >> 3);
    unsigned ka, kb; int Nh, head;
    if (c < 238)      { ka = NK0.a; kb = NK0.b; Nh = 8;  head = c - 230; }
    else if (c < 240) { ka = NK1.a; kb = NK1.b; Nh = 2;  head = c - 238; }
    else              { ka = NK2.a; kb = NK2.b; Nh = 54; head = c - 240; }
    #pragma unroll
    for (int q = 0; q < 2; ++q) {
      int rb = (tid & 7) * 4 + q * 32;
      float vbuf[4];
      #pragma unroll
      for (int e = 0; e < 4; ++e) {
        int rl = rb + e;
        float x = outs[rl * 321 + c];
        unsigned j = (unsigned)((r0 + rl) * Nh + head);
        TF2 t = threefry2x32(ka, kb, 0u, j);
        unsigned bits = t.a ^ t.b;
        float u  = __uint_as_float((bits >> 9) | 0x3f800000u) - 1.0f;
        float gn = -logf(-logf(u + 1e-20f) + 1e-20f);
        vbuf[e] = 1.0f / (1.0f + expf(-(x + gn)));
      }
      *(float4*)(out + (size_t)B_ROWS * c + r0 + rb) = *(float4*)vbuf;
    }
  }
}

// ---------------- launch ----------------
extern "C" void kernel_launch(void* const* d_in, const int* in_sizes, int n_in,
                              void* d_out, int out_size, void* d_ws, size_t ws_size,
                              hipStream_t stream) {
  const float* z     = (const float*)d_in[0];
  const float* W1    = (const float*)d_in[1];
  const float* b1    = (const float*)d_in[2];
  const float* Wnum  = (const float*)d_in[3];
  const float* bnum  = (const float*)d_in[4];
  const float* Wcat  = (const float*)d_in[5];
  const float* bcat  = (const float*)d_in[6];
  const float* Wbin  = (const float*)d_in[7];
  const float* bbin  = (const float*)d_in[8];
  const float* Wlike = (const float*)d_in[9];
  const float* blike = (const float*)d_in[10];
  const float* Wmask = (const float*)d_in[11];
  const float* bmask = (const float*)d_in[12];

  unsigned short* W1p   = (unsigned short*)d_ws;            // 131072 bf16
  unsigned short* Wallp = W1p + 131072;                     // 327680 bf16
  float*          ball  = (float*)(Wallp + 327680);         // 320 f32

  const int total = 16384 + 40960 + 320;
  prep_kernel<<<(total + 255) / 256, 256, 0, stream>>>(
      W1, Wnum, Wcat, Wbin, Wlike, Wmask, bnum, bcat, bbin, blike, bmask,
      W1p, Wallp, ball);

  decoder_kernel<<<B_ROWS / 64, 512, 0, stream>>>(
      z, b1, W1p, Wallp, ball, (float*)d_out);
}